// Round 1
// baseline (110.944 us; speedup 1.0000x reference)
//
#include <hip/hip_runtime.h>
#include <hip/hip_bf16.h>

typedef short v8s __attribute__((ext_vector_type(8)));
typedef float v4f __attribute__((ext_vector_type(4)));

#define NN 1024
#define MM 32
#define DD 256
#define NMROWS (NN * MM)

__device__ __forceinline__ unsigned short f2bf(float f) {
    unsigned u = __float_as_uint(f);
    unsigned r = (u + 0x7fffu + ((u >> 16) & 1u)) >> 16;
    return (unsigned short)r;
}
__device__ __forceinline__ float bf2f(unsigned short s) {
    return __uint_as_float(((unsigned)s) << 16);
}

// Kernel 1: per-speaker centroids (scaled by kappa/M into bf16), e->bf16 copy,
// exact fp32 sigma_own and bf16-matched sigma_wrong per row.
__global__ __launch_bounds__(256) void k_centroid(
    const float* __restrict__ e, const float* __restrict__ wp,
    unsigned short* __restrict__ c_scaled,   // [NN][DD] bf16 bits, = bf16(kappa * s / M)
    unsigned short* __restrict__ e_bf,       // [NMROWS][DD] bf16 bits
    float* __restrict__ sig_own, float* __restrict__ sig_wrong)
{
    __shared__ float es[MM][260];    // +4 pad breaks 256-dword bank aliasing
    __shared__ float s_l[DD];
    __shared__ unsigned short cb[DD];
    const int n = blockIdx.x, t = threadIdx.x;
    const float kappa = wp[0] * 1.44269504088896340736f;
    const float* eb0 = e + (size_t)n * MM * DD;

    // stage 32x256 fp32 -> LDS, and write bf16 copy to global
    for (int r = 0; r < 8; ++r) {
        int id = r * 256 + t;              // 0..2047 float4 chunks
        int m = id >> 6, c4 = (id & 63) << 2;
        float4 v = *reinterpret_cast<const float4*>(eb0 + m * DD + c4);
        *reinterpret_cast<float4*>(&es[m][c4]) = v;
        ushort4 bv;
        bv.x = f2bf(v.x); bv.y = f2bf(v.y); bv.z = f2bf(v.z); bv.w = f2bf(v.w);
        *reinterpret_cast<ushort4*>(e_bf + (size_t)(n * MM + m) * DD + c4) = bv;
    }
    __syncthreads();

    // centroid sum over m for d = t; write scaled bf16 centroid
    {
        float s = 0.f;
        #pragma unroll
        for (int m = 0; m < MM; ++m) s += es[m][t];
        s_l[t] = s;
        unsigned short cv = f2bf(s * (kappa / (float)MM));
        cb[t] = cv;
        c_scaled[n * DD + t] = cv;
    }
    __syncthreads();

    // per-row dots: 8 threads per row
    const int m = t >> 3, j = t & 7;
    float a1 = 0.f, a2 = 0.f, a3 = 0.f;
    #pragma unroll
    for (int ii = 0; ii < 32; ++ii) {
        int d = j + (ii << 3);
        float ev = es[m][d];
        a1 += ev * s_l[d];
        a2 += ev * ev;
        a3 += bf2f(f2bf(ev)) * bf2f(cb[d]);
    }
    a1 += __shfl_xor(a1, 1, 8); a1 += __shfl_xor(a1, 2, 8); a1 += __shfl_xor(a1, 4, 8);
    a2 += __shfl_xor(a2, 1, 8); a2 += __shfl_xor(a2, 2, 8); a2 += __shfl_xor(a2, 4, 8);
    a3 += __shfl_xor(a3, 1, 8); a3 += __shfl_xor(a3, 2, 8); a3 += __shfl_xor(a3, 4, 8);
    if (j == 0) {
        int row = n * MM + m;
        sig_own[row]   = kappa * (a1 - a2) * (1.0f / (float)(MM - 1));
        sig_wrong[row] = a3;   // kappa already folded into cb
    }
}

// Kernel 2: fused sim-GEMM + exp-sum. Block = 128 rows x 512 cols.
// Wave = 32 rows (2 MFMA row-tiles), A-frags register-resident for whole block.
__global__ __launch_bounds__(256, 2) void k_gemm(
    const unsigned short* __restrict__ e_bf,
    const unsigned short* __restrict__ c_scaled,
    float* __restrict__ partS)               // [2][NMROWS]
{
    __shared__ unsigned short lc[64 * 264];  // 64 centroids x (256 + 8 pad) bf16
    const int t = threadIdx.x;
    const int wave = t >> 6, lane = t & 63;
    const int r16 = lane & 15, q = lane >> 4;
    const int rowblk = blockIdx.x >> 1, colchunk = blockIdx.x & 1;
    const int row0 = rowblk * 128, col0 = colchunk * 512;

    // A fragments: A[m=lane&15][k=(lane>>4)*8+j], 2 row-tiles x 8 k-steps
    v8s A[2][8];
    #pragma unroll
    for (int rt = 0; rt < 2; ++rt) {
        const unsigned short* ap =
            e_bf + (size_t)(row0 + wave * 32 + rt * 16 + r16) * DD + q * 8;
        #pragma unroll
        for (int kb = 0; kb < 8; ++kb)
            A[rt][kb] = *reinterpret_cast<const v8s*>(ap + kb * 32);
    }

    float sums[2][4] = {};
    for (int it = 0; it < 8; ++it) {
        const int ct0 = col0 + it * 64;
        // stage 64x256 bf16 C tile into padded LDS
        #pragma unroll
        for (int r = 0; r < 8; ++r) {
            int id = r * 256 + t;            // 0..2047 16B chunks
            int crow = id >> 5, ch = id & 31;
            v8s v = *reinterpret_cast<const v8s*>(
                c_scaled + (size_t)(ct0 + crow) * DD + ch * 8);
            *reinterpret_cast<v8s*>(&lc[crow * 264 + ch * 8]) = v;
        }
        __syncthreads();

        v4f acc[2][4] = {};
        #pragma unroll
        for (int kb = 0; kb < 8; ++kb) {
            v8s b[4];
            #pragma unroll
            for (int ct = 0; ct < 4; ++ct)
                b[ct] = *reinterpret_cast<const v8s*>(
                    &lc[(ct * 16 + r16) * 264 + kb * 32 + q * 8]);
            #pragma unroll
            for (int rt = 0; rt < 2; ++rt)
                #pragma unroll
                for (int ct = 0; ct < 4; ++ct)
                    acc[rt][ct] = __builtin_amdgcn_mfma_f32_16x16x32_bf16(
                        A[rt][kb], b[ct], acc[rt][ct], 0, 0, 0);
        }
        #pragma unroll
        for (int rt = 0; rt < 2; ++rt)
            #pragma unroll
            for (int ct = 0; ct < 4; ++ct)
                #pragma unroll
                for (int i = 0; i < 4; ++i)
                    sums[rt][i] += exp2f(acc[rt][ct][i]);
        __syncthreads();
    }

    // D layout: col = lane&15, row = (lane>>4)*4 + reg. Reduce over the 16 col-lanes.
    #pragma unroll
    for (int rt = 0; rt < 2; ++rt)
        #pragma unroll
        for (int i = 0; i < 4; ++i) {
            float v = sums[rt][i];
            v += __shfl_xor(v, 1, 16);
            v += __shfl_xor(v, 2, 16);
            v += __shfl_xor(v, 4, 16);
            v += __shfl_xor(v, 8, 16);
            sums[rt][i] = v;
        }
    if (r16 == 0) {
        #pragma unroll
        for (int rt = 0; rt < 2; ++rt)
            #pragma unroll
            for (int i = 0; i < 4; ++i) {
                int row = row0 + wave * 32 + rt * 16 + q * 4 + i;
                partS[colchunk * NMROWS + row] = sums[rt][i];
            }
    }
}

// Kernel 3: per-row LSE with exact-diagonal swap, reduce to scalar loss.
__global__ __launch_bounds__(256) void k_loss(
    const float* __restrict__ partS, const float* __restrict__ sig_own,
    const float* __restrict__ sig_wrong, float* __restrict__ out)
{
    const int t = threadIdx.x;
    const int row = blockIdx.x * 256 + t;
    float S  = partS[row] + partS[NMROWS + row];
    float so = sig_own[row], sw = sig_wrong[row];
    float Sp = S - exp2f(sw) + exp2f(so);
    float lr = 0.69314718055994530942f * (log2f(Sp) - so);
    #pragma unroll
    for (int off = 1; off < 64; off <<= 1) lr += __shfl_xor(lr, off, 64);
    __shared__ float ws4[4];
    if ((t & 63) == 0) ws4[t >> 6] = lr;
    __syncthreads();
    if (t == 0) {
        float tot = ws4[0] + ws4[1] + ws4[2] + ws4[3];
        atomicAdd(out, tot * (1.0f / (float)NMROWS));
    }
}

extern "C" void kernel_launch(void* const* d_in, const int* in_sizes, int n_in,
                              void* d_out, int out_size, void* d_ws, size_t ws_size,
                              hipStream_t stream)
{
    const float* e = (const float*)d_in[0];
    const float* w = (const float*)d_in[1];
    char* ws = (char*)d_ws;

    unsigned short* c_scaled = (unsigned short*)ws;                       // 512 KB
    unsigned short* e_bf     = (unsigned short*)(ws + (size_t)(1 << 19)); // 16 MB
    float* sig_own   = (float*)(ws + (size_t)(1 << 19) + (size_t)NMROWS * DD * 2);
    float* sig_wrong = sig_own + NMROWS;
    float* partS     = sig_wrong + NMROWS;                                // [2][NMROWS]
    float* outf = (float*)d_out;

    hipMemsetAsync(d_out, 0, sizeof(float), stream);
    hipLaunchKernelGGL(k_centroid, dim3(NN), dim3(256), 0, stream,
                       e, w, c_scaled, e_bf, sig_own, sig_wrong);
    hipLaunchKernelGGL(k_gemm, dim3(512), dim3(256), 0, stream,
                       e_bf, c_scaled, partS);
    hipLaunchKernelGGL(k_loss, dim3(NMROWS / 256), dim3(256), 0, stream,
                       partS, sig_own, sig_wrong, outf);
}

// Round 2
// 108.896 us; speedup vs baseline: 1.0188x; 1.0188x over previous
//
#include <hip/hip_runtime.h>
#include <hip/hip_bf16.h>

typedef short v8s __attribute__((ext_vector_type(8)));
typedef float v4f __attribute__((ext_vector_type(4)));

#define NN 1024
#define MM 32
#define DD 256
#define NMROWS (NN * MM)

__device__ __forceinline__ unsigned short f2bf(float f) {
    unsigned u = __float_as_uint(f);
    unsigned r = (u + 0x7fffu + ((u >> 16) & 1u)) >> 16;
    return (unsigned short)r;
}

// Kernel 1: per-speaker centroids (scaled by kappa/M into bf16), e->bf16 copy,
// exact fp32 sigma_own per row. (Diagonal exclusion moved into k_gemm.)
__global__ __launch_bounds__(256) void k_centroid(
    const float* __restrict__ e, const float* __restrict__ wp,
    unsigned short* __restrict__ c_scaled,   // [NN][DD] bf16 bits = bf16(kappa * s / M)
    unsigned short* __restrict__ e_bf,       // [NMROWS][DD] bf16 bits
    float* __restrict__ sig_own)
{
    __shared__ float es[MM][260];    // +4 pad: row stride 260 ≡ 4 mod 32 banks
    __shared__ float s_l[DD];
    const int n = blockIdx.x, t = threadIdx.x;
    const float kappa = wp[0] * 1.44269504088896340736f;
    const float* eb0 = e + (size_t)n * MM * DD;

    // stage 32x256 fp32 -> LDS, and write bf16 copy to global
    for (int r = 0; r < 8; ++r) {
        int id = r * 256 + t;              // 0..2047 float4 chunks
        int m = id >> 6, c4 = (id & 63) << 2;
        float4 v = *reinterpret_cast<const float4*>(eb0 + m * DD + c4);
        *reinterpret_cast<float4*>(&es[m][c4]) = v;
        ushort4 bv;
        bv.x = f2bf(v.x); bv.y = f2bf(v.y); bv.z = f2bf(v.z); bv.w = f2bf(v.w);
        *reinterpret_cast<ushort4*>(e_bf + (size_t)(n * MM + m) * DD + c4) = bv;
    }
    __syncthreads();

    // centroid sum over m for d = t; write scaled bf16 centroid
    {
        float s = 0.f;
        #pragma unroll
        for (int m = 0; m < MM; ++m) s += es[m][t];
        s_l[t] = s;
        c_scaled[n * DD + t] = f2bf(s * (kappa / (float)MM));
    }
    __syncthreads();

    // per-row exact fp32 LOO dot: 8 threads per row
    const int m = t >> 3, j = t & 7;
    float a1 = 0.f, a2 = 0.f;
    #pragma unroll
    for (int ii = 0; ii < 32; ++ii) {
        int d = j + (ii << 3);
        float ev = es[m][d];
        a1 += ev * s_l[d];
        a2 += ev * ev;
    }
    a1 += __shfl_xor(a1, 1, 8); a1 += __shfl_xor(a1, 2, 8); a1 += __shfl_xor(a1, 4, 8);
    a2 += __shfl_xor(a2, 1, 8); a2 += __shfl_xor(a2, 2, 8); a2 += __shfl_xor(a2, 4, 8);
    if (j == 0)
        sig_own[n * MM + m] = kappa * (a1 - a2) * (1.0f / (float)(MM - 1));
}

// Kernel 2: fused sim-GEMM + exp-sum with diagonal exclusion and register
// double-buffer prefetch of the C tile. Block = 128 rows x 512 cols.
__global__ __launch_bounds__(256, 2) void k_gemm(
    const unsigned short* __restrict__ e_bf,
    const unsigned short* __restrict__ c_scaled,
    float* __restrict__ partS)               // [2][NMROWS]
{
    __shared__ unsigned short lc[64 * 264];  // 64 centroids x (256 + 8 pad) bf16
    const int t = threadIdx.x;
    const int wave = t >> 6, lane = t & 63;
    const int r16 = lane & 15, q = lane >> 4;
    const int rowblk = blockIdx.x >> 1, colchunk = blockIdx.x & 1;
    const int row0 = rowblk * 128, col0 = colchunk * 512;

    // A fragments: A[m=lane&15][k=(lane>>4)*8+j], register-resident for whole block
    v8s A[2][8];
    #pragma unroll
    for (int rt = 0; rt < 2; ++rt) {
        const unsigned short* ap =
            e_bf + (size_t)(row0 + wave * 32 + rt * 16 + r16) * DD + q * 8;
        #pragma unroll
        for (int kb = 0; kb < 8; ++kb)
            A[rt][kb] = *reinterpret_cast<const v8s*>(ap + kb * 32);
    }

    // speaker id per rt-tile (uniform across the tile's 16 rows)
    const int spk0 = (row0 + wave * 32) >> 5;
    const int spk1 = (row0 + wave * 32 + 16) >> 5;

    // staging: thread t owns chunks {t + r*256}: crow = r*8 + (t>>5), ch = t&31
    const unsigned short* gbase = c_scaled + (size_t)(col0 + (t >> 5)) * DD + (t & 31) * 8;
    unsigned short* lbase = &lc[(t >> 5) * 264 + (t & 31) * 8];

    v8s pf[2][8];
    #pragma unroll
    for (int r = 0; r < 8; ++r)
        pf[0][r] = *reinterpret_cast<const v8s*>(gbase + (size_t)(r * 8) * DD);

    float sums[2][4] = {};
    #pragma unroll
    for (int it = 0; it < 8; ++it) {
        const int cur = it & 1, nxt = cur ^ 1;
        __syncthreads();                     // previous tile's consumers done
        #pragma unroll
        for (int r = 0; r < 8; ++r)
            *reinterpret_cast<v8s*>(lbase + r * 8 * 264) = pf[cur][r];
        __syncthreads();
        if (it < 7) {                        // prefetch next tile under MFMA shadow
            const unsigned short* gp = gbase + (size_t)((it + 1) * 64) * DD;
            #pragma unroll
            for (int r = 0; r < 8; ++r)
                pf[nxt][r] = *reinterpret_cast<const v8s*>(gp + (size_t)(r * 8) * DD);
        }

        v4f acc[2][4] = {};
        #pragma unroll
        for (int kb = 0; kb < 8; ++kb) {
            v8s b[4];
            #pragma unroll
            for (int ct = 0; ct < 4; ++ct)
                b[ct] = *reinterpret_cast<const v8s*>(
                    &lc[(ct * 16 + r16) * 264 + kb * 32 + q * 8]);
            #pragma unroll
            for (int rt = 0; rt < 2; ++rt)
                #pragma unroll
                for (int ct = 0; ct < 4; ++ct)
                    acc[rt][ct] = __builtin_amdgcn_mfma_f32_16x16x32_bf16(
                        A[rt][kb], b[ct], acc[rt][ct], 0, 0, 0);
        }
        const int ct0 = col0 + it * 64;
        #pragma unroll
        for (int ct = 0; ct < 4; ++ct) {
            const int col = ct0 + ct * 16 + r16;    // D layout: col = lane&15
            const bool skip0 = (col == spk0), skip1 = (col == spk1);
            #pragma unroll
            for (int i = 0; i < 4; ++i) {
                float e0 = __builtin_amdgcn_exp2f(acc[0][ct][i]);
                float e1 = __builtin_amdgcn_exp2f(acc[1][ct][i]);
                sums[0][i] += skip0 ? 0.f : e0;
                sums[1][i] += skip1 ? 0.f : e1;
            }
        }
    }

    // D layout: row = (lane>>4)*4 + reg. Reduce over the 16 col-lanes.
    #pragma unroll
    for (int rt = 0; rt < 2; ++rt)
        #pragma unroll
        for (int i = 0; i < 4; ++i) {
            float v = sums[rt][i];
            v += __shfl_xor(v, 1, 16);
            v += __shfl_xor(v, 2, 16);
            v += __shfl_xor(v, 4, 16);
            v += __shfl_xor(v, 8, 16);
            sums[rt][i] = v;
        }
    if (r16 == 0) {
        #pragma unroll
        for (int rt = 0; rt < 2; ++rt)
            #pragma unroll
            for (int i = 0; i < 4; ++i) {
                int row = row0 + wave * 32 + rt * 16 + q * 4 + i;
                partS[colchunk * NMROWS + row] = sums[rt][i];
            }
    }
}

// Kernel 3: per-row LSE (diagonal already excluded in k2), reduce to scalar loss.
__global__ __launch_bounds__(256) void k_loss(
    const float* __restrict__ partS, const float* __restrict__ sig_own,
    float* __restrict__ out)
{
    const int t = threadIdx.x;
    const int row = blockIdx.x * 256 + t;
    float S  = partS[row] + partS[NMROWS + row];
    float so = sig_own[row];
    float Sp = S + __builtin_amdgcn_exp2f(so);
    float lr = 0.69314718055994530942f * (__builtin_amdgcn_logf(Sp) - so);
    #pragma unroll
    for (int off = 1; off < 64; off <<= 1) lr += __shfl_xor(lr, off, 64);
    __shared__ float ws4[4];
    if ((t & 63) == 0) ws4[t >> 6] = lr;
    __syncthreads();
    if (t == 0) {
        float tot = ws4[0] + ws4[1] + ws4[2] + ws4[3];
        atomicAdd(out, tot * (1.0f / (float)NMROWS));
    }
}

extern "C" void kernel_launch(void* const* d_in, const int* in_sizes, int n_in,
                              void* d_out, int out_size, void* d_ws, size_t ws_size,
                              hipStream_t stream)
{
    const float* e = (const float*)d_in[0];
    const float* w = (const float*)d_in[1];
    char* ws = (char*)d_ws;

    unsigned short* c_scaled = (unsigned short*)ws;                       // 512 KB
    unsigned short* e_bf     = (unsigned short*)(ws + (size_t)(1 << 19)); // 16 MB
    float* sig_own = (float*)(ws + (size_t)(1 << 19) + (size_t)NMROWS * DD * 2);
    float* partS   = sig_own + NMROWS;                                    // [2][NMROWS]
    float* outf = (float*)d_out;

    hipMemsetAsync(d_out, 0, sizeof(float), stream);
    hipLaunchKernelGGL(k_centroid, dim3(NN), dim3(256), 0, stream,
                       e, w, c_scaled, e_bf, sig_own);
    hipLaunchKernelGGL(k_gemm, dim3(512), dim3(256), 0, stream,
                       e_bf, c_scaled, partS);
    hipLaunchKernelGGL(k_loss, dim3(NMROWS / 256), dim3(256), 0, stream,
                       partS, sig_own, outf);
}